// Round 1
// baseline (1178.731 us; speedup 1.0000x reference)
//
#include <hip/hip_runtime.h>
#include <hip/hip_bf16.h>

// ---------------- CSR build ----------------

__global__ void k_count(const int* __restrict__ dst, int E, int* __restrict__ cnt) {
    int e = blockIdx.x * blockDim.x + threadIdx.x;
    if (e < E) atomicAdd(&cnt[dst[e]], 1);
}

__global__ void k_dinv(const int* __restrict__ cnt, float* __restrict__ dinv, int N,
                       const int* __restrict__ batch, int* __restrict__ cntg) {
    int i = blockIdx.x * blockDim.x + threadIdx.x;
    if (i < N) {
        dinv[i] = rsqrtf((float)(cnt[i] + 1));  // +1 self-loop
        atomicAdd(&cntg[batch[i]], 1);
    }
}

__global__ __launch_bounds__(1024) void k_scan1(const int* __restrict__ cnt, int N,
                                                int* __restrict__ rp, int* __restrict__ bsum) {
    __shared__ int s[1024];
    int t = threadIdx.x;
    int i = blockIdx.x * 1024 + t;
    int v = (i < N) ? cnt[i] : 0;
    s[t] = v;
    __syncthreads();
    for (int off = 1; off < 1024; off <<= 1) {
        int u = (t >= off) ? s[t - off] : 0;
        __syncthreads();
        s[t] += u;
        __syncthreads();
    }
    if (i < N) rp[i] = s[t] - v;  // exclusive within block
    if (t == 1023) bsum[blockIdx.x] = s[1023];
}

__global__ __launch_bounds__(1024) void k_scan2(const int* __restrict__ bsum, int NB,
                                                int* __restrict__ boff) {
    __shared__ int s[1024];
    int t = threadIdx.x;
    int v = (t < NB) ? bsum[t] : 0;
    s[t] = v;
    __syncthreads();
    for (int off = 1; off < 1024; off <<= 1) {
        int u = (t >= off) ? s[t - off] : 0;
        __syncthreads();
        s[t] += u;
        __syncthreads();
    }
    if (t < NB) boff[t] = s[t] - v;
}

__global__ void k_scan3(int* __restrict__ rp, const int* __restrict__ boff, int N, int E,
                        int* __restrict__ cursor) {
    int i = blockIdx.x * blockDim.x + threadIdx.x;
    if (i < N) {
        int v = rp[i] + boff[i >> 10];
        rp[i] = v;
        cursor[i] = v;
    }
    if (blockIdx.x == 0 && threadIdx.x == 0) rp[N] = E;
}

__global__ void k_fill(const int* __restrict__ src, const int* __restrict__ dst, int E,
                       int* __restrict__ cursor, int* __restrict__ colx) {
    int e = blockIdx.x * blockDim.x + threadIdx.x;
    if (e < E) {
        int d = dst[e];
        int pos = atomicAdd(&cursor[d], 1);
        colx[pos] = src[e];
    }
}

__global__ __launch_bounds__(256) void k_gscan(const int* __restrict__ cntg, int G, int N,
                                               int* __restrict__ gptr) {
    __shared__ int s[256];
    int t = threadIdx.x;
    int v = (t < G) ? cntg[t] : 0;
    s[t] = v;
    __syncthreads();
    for (int off = 1; off < 256; off <<= 1) {
        int u = (t >= off) ? s[t - off] : 0;
        __syncthreads();
        s[t] += u;
        __syncthreads();
    }
    if (t < G) gptr[t] = s[t] - v;
    if (t == 0) gptr[G] = N;
}

// ---------------- GEMM: out[row] = (act(X[row]) @ W) * dinv[row] ----------------
// act = identity (layer 1) or BN+ReLU (layer 2). K = 128, Cout = 128.
// Block: 256 threads, 64 rows. Thread (t): rows 2*(t>>3), 2*(t>>3)+1;
// cols q*32 + (t&7)*4 + {0..3}, q in 0..3 (conflict-free LDS float4 reads).

template <bool BN>
__global__ __launch_bounds__(256) void k_gemm(const float* __restrict__ X,
                                              const float* __restrict__ W,
                                              const float* __restrict__ scale,
                                              const float* __restrict__ shift,
                                              const float* __restrict__ dinv,
                                              float* __restrict__ out, int N) {
    __shared__ float Ws[128 * 128];
    __shared__ float sc[128], sh[128];
    int t = threadIdx.x;
    {
        const float4* W4 = (const float4*)W;
        float4* Ws4 = (float4*)Ws;
        #pragma unroll
        for (int i = 0; i < 16; i++) Ws4[t + i * 256] = W4[t + i * 256];
        if (BN && t < 128) { sc[t] = scale[t]; sh[t] = shift[t]; }
    }
    __syncthreads();

    int r0 = blockIdx.x * 64 + (t >> 3) * 2;
    int r1 = r0 + 1;
    bool v0 = r0 < N, v1 = r1 < N;
    const float* x0 = X + (size_t)(v0 ? r0 : N - 1) * 128;
    const float* x1 = X + (size_t)(v1 ? r1 : N - 1) * 128;
    int cbase = (t & 7) * 4;

    float acc0[16], acc1[16];
    #pragma unroll
    for (int j = 0; j < 16; j++) { acc0[j] = 0.f; acc1[j] = 0.f; }

    for (int kk = 0; kk < 128; kk += 4) {
        float4 a4 = *(const float4*)(x0 + kk);
        float4 b4 = *(const float4*)(x1 + kk);
        float av[4] = {a4.x, a4.y, a4.z, a4.w};
        float bv[4] = {b4.x, b4.y, b4.z, b4.w};
        #pragma unroll
        for (int j = 0; j < 4; j++) {
            float a = av[j], b = bv[j];
            if (BN) {
                float s = sc[kk + j], h = sh[kk + j];
                a = fmaxf(fmaf(a, s, h), 0.f);
                b = fmaxf(fmaf(b, s, h), 0.f);
            }
            const float* wrow = Ws + (kk + j) * 128 + cbase;
            #pragma unroll
            for (int q = 0; q < 4; q++) {
                float4 w = *(const float4*)(wrow + q * 32);
                acc0[q * 4 + 0] = fmaf(a, w.x, acc0[q * 4 + 0]);
                acc0[q * 4 + 1] = fmaf(a, w.y, acc0[q * 4 + 1]);
                acc0[q * 4 + 2] = fmaf(a, w.z, acc0[q * 4 + 2]);
                acc0[q * 4 + 3] = fmaf(a, w.w, acc0[q * 4 + 3]);
                acc1[q * 4 + 0] = fmaf(b, w.x, acc1[q * 4 + 0]);
                acc1[q * 4 + 1] = fmaf(b, w.y, acc1[q * 4 + 1]);
                acc1[q * 4 + 2] = fmaf(b, w.z, acc1[q * 4 + 2]);
                acc1[q * 4 + 3] = fmaf(b, w.w, acc1[q * 4 + 3]);
            }
        }
    }

    if (v0) {
        float d = dinv[r0];
        float* o = out + (size_t)r0 * 128 + cbase;
        #pragma unroll
        for (int q = 0; q < 4; q++) {
            float4 w = make_float4(acc0[q * 4 + 0] * d, acc0[q * 4 + 1] * d,
                                   acc0[q * 4 + 2] * d, acc0[q * 4 + 3] * d);
            *(float4*)(o + q * 32) = w;
        }
    }
    if (v1) {
        float d = dinv[r1];
        float* o = out + (size_t)r1 * 128 + cbase;
        #pragma unroll
        for (int q = 0; q < 4; q++) {
            float4 w = make_float4(acc1[q * 4 + 0] * d, acc1[q * 4 + 1] * d,
                                   acc1[q * 4 + 2] * d, acc1[q * 4 + 3] * d);
            *(float4*)(o + q * 32) = w;
        }
    }
}

// ---------------- Aggregation: out[i] = dinv[i]*(hs[i] + sum_{j in in(i)} hs[j]) + b ----------------
// One wave per node; lane L holds cols {2L, 2L+1} as float2.

__global__ __launch_bounds__(256) void k_agg(const float* __restrict__ hs,
                                             const int* __restrict__ rp,
                                             const int* __restrict__ colx,
                                             const float* __restrict__ dinv,
                                             const float* __restrict__ bias,
                                             float* __restrict__ out, int N) {
    int wave = (blockIdx.x * 256 + threadIdx.x) >> 6;
    int lane = threadIdx.x & 63;
    if (wave >= N) return;
    int i = wave;
    const float2* base = (const float2*)hs;
    float2 acc = base[(size_t)i * 64 + lane];
    float2 acc2 = make_float2(0.f, 0.f);
    int k0 = rp[i], k1 = rp[i + 1];
    int k = k0;
    for (; k + 1 < k1; k += 2) {
        int j0 = colx[k];
        int j1 = colx[k + 1];
        float2 v0 = base[(size_t)j0 * 64 + lane];
        float2 v1 = base[(size_t)j1 * 64 + lane];
        acc.x += v0.x; acc.y += v0.y;
        acc2.x += v1.x; acc2.y += v1.y;
    }
    if (k < k1) {
        int j0 = colx[k];
        float2 v0 = base[(size_t)j0 * 64 + lane];
        acc.x += v0.x; acc.y += v0.y;
    }
    acc.x += acc2.x; acc.y += acc2.y;
    float d = dinv[i];
    float2 b = ((const float2*)bias)[lane];
    float2 o;
    o.x = fmaf(acc.x, d, b.x);
    o.y = fmaf(acc.y, d, b.y);
    ((float2*)out)[(size_t)i * 64 + lane] = o;
}

// ---------------- BN stats: sums[c] = sum_i x[i][c], sums[128+c] = sum_i x[i][c]^2 ----------------

__global__ __launch_bounds__(256) void k_stats(const float* __restrict__ x, int N,
                                               float* __restrict__ sums) {
    int lane = threadIdx.x & 63;
    int wv = threadIdx.x >> 6;
    int gw = blockIdx.x * 4 + wv;
    int stride = gridDim.x * 4;
    const float2* b = (const float2*)x;
    float2 s = make_float2(0.f, 0.f), q = make_float2(0.f, 0.f);
    for (int i = gw; i < N; i += stride) {
        float2 v = b[(size_t)i * 64 + lane];
        s.x += v.x; s.y += v.y;
        q.x += v.x * v.x; q.y += v.y * v.y;
    }
    __shared__ float ls[4][128];
    __shared__ float lq[4][128];
    ls[wv][2 * lane] = s.x; ls[wv][2 * lane + 1] = s.y;
    lq[wv][2 * lane] = q.x; lq[wv][2 * lane + 1] = q.y;
    __syncthreads();
    int t = threadIdx.x;
    if (t < 128) {
        float ts = ls[0][t] + ls[1][t] + ls[2][t] + ls[3][t];
        float tq = lq[0][t] + lq[1][t] + lq[2][t] + lq[3][t];
        atomicAdd(&sums[t], ts);
        atomicAdd(&sums[128 + t], tq);
    }
}

__global__ void k_bnp(const float* __restrict__ sums, const float* __restrict__ g,
                      const float* __restrict__ be, int N, float* __restrict__ scale,
                      float* __restrict__ shift) {
    int c = threadIdx.x;
    if (c < 128) {
        float invN = 1.0f / (float)N;
        float mu = sums[c] * invN;
        float var = sums[128 + c] * invN - mu * mu;
        var = fmaxf(var, 0.f);
        float s = g[c] * rsqrtf(var + 1e-5f);
        scale[c] = s;
        shift[c] = fmaf(-mu, s, be[c]);
    }
}

// ---------------- Pooling: one block per graph ----------------

__global__ __launch_bounds__(256) void k_pool(const float* __restrict__ x,
                                              const int* __restrict__ gptr,
                                              const float* __restrict__ scale,
                                              const float* __restrict__ shift,
                                              float* __restrict__ pooled) {
    int g = blockIdx.x;
    int t = threadIdx.x;
    int c = t & 127, half = t >> 7;
    int r0 = gptr[g], r1 = gptr[g + 1];
    float s = scale[c], h = shift[c];
    float acc = 0.f;
    for (int r = r0 + half; r < r1; r += 2) {
        float v = x[(size_t)r * 128 + c];
        acc += fmaxf(fmaf(v, s, h), 0.f);
    }
    __shared__ float ls[256];
    ls[t] = acc;
    __syncthreads();
    if (t < 128) {
        float tot = ls[t] + ls[t + 128];
        float cntf = (float)(r1 - r0);
        pooled[g * 128 + t] = tot / fmaxf(cntf, 1.f);
    }
}

// ---------------- Head: out[g][o] = pooled[g] @ Wout[:,o] + bout[o] ----------------

__global__ __launch_bounds__(64) void k_final(const float* __restrict__ pooled,
                                              const float* __restrict__ Wout,
                                              const float* __restrict__ bout,
                                              float* __restrict__ out, int O) {
    int g = blockIdx.x, o = threadIdx.x;
    float acc = bout[o];
    for (int c = 0; c < 128; c++) acc = fmaf(pooled[g * 128 + c], Wout[c * O + o], acc);
    out[g * O + o] = acc;
}

// ---------------- Host launch ----------------

extern "C" void kernel_launch(void* const* d_in, const int* in_sizes, int n_in,
                              void* d_out, int out_size, void* d_ws, size_t ws_size,
                              hipStream_t stream) {
    const float* x    = (const float*)d_in[0];
    const int*   edge = (const int*)d_in[1];
    const int*   batch= (const int*)d_in[2];
    const float* W0   = (const float*)d_in[4];
    const float* b0   = (const float*)d_in[5];
    const float* g0   = (const float*)d_in[6];
    const float* be0  = (const float*)d_in[7];
    const float* W1   = (const float*)d_in[8];
    const float* b1   = (const float*)d_in[9];
    const float* g1   = (const float*)d_in[10];
    const float* be1  = (const float*)d_in[11];
    const float* Wout = (const float*)d_in[12];
    const float* bout = (const float*)d_in[13];
    float* out = (float*)d_out;

    const int Hh  = in_sizes[5];              // 128
    const int Fin = in_sizes[4] / Hh;         // 128
    const int N   = in_sizes[0] / Fin;        // 100000
    const int E   = in_sizes[1] / 2;          // 1600000
    const int O   = in_sizes[13];             // 64
    const int G   = out_size / O;             // 128
    (void)Hh; (void)n_in; (void)ws_size;

    char* p = (char*)d_ws;
    auto alloc = [&](size_t bytes) -> void* {
        void* r = (void*)p;
        p += (bytes + 255) & ~(size_t)255;
        return r;
    };
    float* A      = (float*)alloc((size_t)N * 128 * 4);
    float* B      = (float*)alloc((size_t)N * 128 * 4);
    float* dinv   = (float*)alloc((size_t)N * 4);
    int*   cnt    = (int*)alloc((size_t)N * 4);
    int*   rp     = (int*)alloc((size_t)(N + 1) * 4);
    int*   cursor = (int*)alloc((size_t)N * 4);
    int*   colx   = (int*)alloc((size_t)E * 4);
    int*   bsum   = (int*)alloc(1024 * 4);
    int*   boff   = (int*)alloc(1024 * 4);
    float* sums   = (float*)alloc(512 * 4);   // [sum1|sq1|sum2|sq2]
    float* bn     = (float*)alloc(512 * 4);   // [scale1|shift1|scale2|shift2]
    int*   cntg   = (int*)alloc((size_t)G * 4);
    int*   gptr   = (int*)alloc((size_t)(G + 1) * 4);
    float* pooled = (float*)alloc((size_t)G * 128 * 4);

    hipMemsetAsync(cnt, 0, (size_t)N * 4, stream);
    hipMemsetAsync(sums, 0, 512 * 4, stream);
    hipMemsetAsync(cntg, 0, (size_t)G * 4, stream);

    const int* src = edge;
    const int* dst = edge + E;

    k_count<<<(E + 255) / 256, 256, 0, stream>>>(dst, E, cnt);
    k_dinv<<<(N + 255) / 256, 256, 0, stream>>>(cnt, dinv, N, batch, cntg);
    int NB = (N + 1023) / 1024;
    k_scan1<<<NB, 1024, 0, stream>>>(cnt, N, rp, bsum);
    k_scan2<<<1, 1024, 0, stream>>>(bsum, NB, boff);
    k_scan3<<<(N + 255) / 256, 256, 0, stream>>>(rp, boff, N, E, cursor);
    k_fill<<<(E + 255) / 256, 256, 0, stream>>>(src, dst, E, cursor, colx);
    k_gscan<<<1, 256, 0, stream>>>(cntg, G, N, gptr);

    // Layer 1
    k_gemm<false><<<(N + 63) / 64, 256, 0, stream>>>(x, W0, nullptr, nullptr, dinv, A, N);
    k_agg<<<(N + 3) / 4, 256, 0, stream>>>(A, rp, colx, dinv, b0, B, N);
    k_stats<<<512, 256, 0, stream>>>(B, N, sums);
    k_bnp<<<1, 128, 0, stream>>>(sums, g0, be0, N, bn, bn + 128);

    // Layer 2 (BN+ReLU fused into GEMM loads)
    k_gemm<true><<<(N + 63) / 64, 256, 0, stream>>>(B, W1, bn, bn + 128, dinv, A, N);
    k_agg<<<(N + 3) / 4, 256, 0, stream>>>(A, rp, colx, dinv, b1, B, N);
    k_stats<<<512, 256, 0, stream>>>(B, N, sums + 256);
    k_bnp<<<1, 128, 0, stream>>>(sums + 256, g1, be1, N, bn + 256, bn + 384);

    // Pool + head (BN+ReLU fused into pooling loads)
    k_pool<<<G, 256, 0, stream>>>(B, gptr, bn + 256, bn + 384, pooled);
    k_final<<<G, 64, 0, stream>>>(pooled, Wout, bout, out, O);
}

// Round 2
// 888.932 us; speedup vs baseline: 1.3260x; 1.3260x over previous
//
#include <hip/hip_runtime.h>
#include <hip/hip_bf16.h>

// ---------------- CSR build ----------------

__global__ void k_count(const int* __restrict__ dst, int E, int* __restrict__ cnt) {
    int e = blockIdx.x * blockDim.x + threadIdx.x;
    if (e < E) atomicAdd(&cnt[dst[e]], 1);
}

__global__ void k_dinv(const int* __restrict__ cnt, float* __restrict__ dinv, int N) {
    int i = blockIdx.x * blockDim.x + threadIdx.x;
    if (i < N) dinv[i] = rsqrtf((float)(cnt[i] + 1));  // +1 self-loop
}

// gptr[g] = first index i where batch[i] >= g (batch is sorted); gptr[G] = N.
__global__ void k_gptr(const int* __restrict__ batch, int N, int G, int* __restrict__ gptr) {
    int g = blockIdx.x * blockDim.x + threadIdx.x;
    if (g > G) return;
    int lo = 0, hi = N;
    while (lo < hi) {
        int mid = (lo + hi) >> 1;
        if (batch[mid] < g) lo = mid + 1; else hi = mid;
    }
    gptr[g] = lo;
}

__global__ __launch_bounds__(1024) void k_scan1(const int* __restrict__ cnt, int N,
                                                int* __restrict__ rp, int* __restrict__ bsum) {
    __shared__ int s[1024];
    int t = threadIdx.x;
    int i = blockIdx.x * 1024 + t;
    int v = (i < N) ? cnt[i] : 0;
    s[t] = v;
    __syncthreads();
    for (int off = 1; off < 1024; off <<= 1) {
        int u = (t >= off) ? s[t - off] : 0;
        __syncthreads();
        s[t] += u;
        __syncthreads();
    }
    if (i < N) rp[i] = s[t] - v;  // exclusive within block
    if (t == 1023) bsum[blockIdx.x] = s[1023];
}

__global__ __launch_bounds__(1024) void k_scan2(const int* __restrict__ bsum, int NB,
                                                int* __restrict__ boff) {
    __shared__ int s[1024];
    int t = threadIdx.x;
    int v = (t < NB) ? bsum[t] : 0;
    s[t] = v;
    __syncthreads();
    for (int off = 1; off < 1024; off <<= 1) {
        int u = (t >= off) ? s[t - off] : 0;
        __syncthreads();
        s[t] += u;
        __syncthreads();
    }
    if (t < NB) boff[t] = s[t] - v;
}

__global__ void k_scan3(int* __restrict__ rp, const int* __restrict__ boff, int N, int E,
                        int* __restrict__ cursor) {
    int i = blockIdx.x * blockDim.x + threadIdx.x;
    if (i < N) {
        int v = rp[i] + boff[i >> 10];
        rp[i] = v;
        cursor[i] = v;
    }
    if (blockIdx.x == 0 && threadIdx.x == 0) rp[N] = E;
}

__global__ void k_fill(const int* __restrict__ src, const int* __restrict__ dst, int E,
                       int* __restrict__ cursor, int* __restrict__ colx) {
    int e = blockIdx.x * blockDim.x + threadIdx.x;
    if (e < E) {
        int d = dst[e];
        int pos = atomicAdd(&cursor[d], 1);
        colx[pos] = src[e];
    }
}

// ---------------- GEMM: out[row] = (act(X[row]) @ W) * dinv[row] ----------------
// act = identity (layer 1) or BN+ReLU (layer 2). K = 128, Cout = 128.
// Block: 256 threads, 64 rows. Thread (t): rows 2*(t>>3), 2*(t>>3)+1;
// cols q*32 + (t&7)*4 + {0..3}, q in 0..3 (conflict-free LDS float4 reads).

template <bool BN>
__global__ __launch_bounds__(256) void k_gemm(const float* __restrict__ X,
                                              const float* __restrict__ W,
                                              const float* __restrict__ scale,
                                              const float* __restrict__ shift,
                                              const float* __restrict__ dinv,
                                              float* __restrict__ out, int N) {
    __shared__ float Ws[128 * 128];
    __shared__ float sc[128], sh[128];
    int t = threadIdx.x;
    {
        const float4* W4 = (const float4*)W;
        float4* Ws4 = (float4*)Ws;
        #pragma unroll
        for (int i = 0; i < 16; i++) Ws4[t + i * 256] = W4[t + i * 256];
        if (BN && t < 128) { sc[t] = scale[t]; sh[t] = shift[t]; }
    }
    __syncthreads();

    int r0 = blockIdx.x * 64 + (t >> 3) * 2;
    int r1 = r0 + 1;
    bool v0 = r0 < N, v1 = r1 < N;
    const float* x0 = X + (size_t)(v0 ? r0 : N - 1) * 128;
    const float* x1 = X + (size_t)(v1 ? r1 : N - 1) * 128;
    int cbase = (t & 7) * 4;

    float acc0[16], acc1[16];
    #pragma unroll
    for (int j = 0; j < 16; j++) { acc0[j] = 0.f; acc1[j] = 0.f; }

    for (int kk = 0; kk < 128; kk += 4) {
        float4 a4 = *(const float4*)(x0 + kk);
        float4 b4 = *(const float4*)(x1 + kk);
        float av[4] = {a4.x, a4.y, a4.z, a4.w};
        float bv[4] = {b4.x, b4.y, b4.z, b4.w};
        #pragma unroll
        for (int j = 0; j < 4; j++) {
            float a = av[j], b = bv[j];
            if (BN) {
                float s = sc[kk + j], h = sh[kk + j];
                a = fmaxf(fmaf(a, s, h), 0.f);
                b = fmaxf(fmaf(b, s, h), 0.f);
            }
            const float* wrow = Ws + (kk + j) * 128 + cbase;
            #pragma unroll
            for (int q = 0; q < 4; q++) {
                float4 w = *(const float4*)(wrow + q * 32);
                acc0[q * 4 + 0] = fmaf(a, w.x, acc0[q * 4 + 0]);
                acc0[q * 4 + 1] = fmaf(a, w.y, acc0[q * 4 + 1]);
                acc0[q * 4 + 2] = fmaf(a, w.z, acc0[q * 4 + 2]);
                acc0[q * 4 + 3] = fmaf(a, w.w, acc0[q * 4 + 3]);
                acc1[q * 4 + 0] = fmaf(b, w.x, acc1[q * 4 + 0]);
                acc1[q * 4 + 1] = fmaf(b, w.y, acc1[q * 4 + 1]);
                acc1[q * 4 + 2] = fmaf(b, w.z, acc1[q * 4 + 2]);
                acc1[q * 4 + 3] = fmaf(b, w.w, acc1[q * 4 + 3]);
            }
        }
    }

    if (v0) {
        float d = dinv[r0];
        float* o = out + (size_t)r0 * 128 + cbase;
        #pragma unroll
        for (int q = 0; q < 4; q++) {
            float4 w = make_float4(acc0[q * 4 + 0] * d, acc0[q * 4 + 1] * d,
                                   acc0[q * 4 + 2] * d, acc0[q * 4 + 3] * d);
            *(float4*)(o + q * 32) = w;
        }
    }
    if (v1) {
        float d = dinv[r1];
        float* o = out + (size_t)r1 * 128 + cbase;
        #pragma unroll
        for (int q = 0; q < 4; q++) {
            float4 w = make_float4(acc1[q * 4 + 0] * d, acc1[q * 4 + 1] * d,
                                   acc1[q * 4 + 2] * d, acc1[q * 4 + 3] * d);
            *(float4*)(o + q * 32) = w;
        }
    }
}

// ---------------- Aggregation: out[i] = dinv[i]*(hs[i] + sum_{j in in(i)} hs[j]) + b ----------------
// One wave per node; lane L holds cols {2L, 2L+1} as float2.

__global__ __launch_bounds__(256) void k_agg(const float* __restrict__ hs,
                                             const int* __restrict__ rp,
                                             const int* __restrict__ colx,
                                             const float* __restrict__ dinv,
                                             const float* __restrict__ bias,
                                             float* __restrict__ out, int N) {
    int wave = (blockIdx.x * 256 + threadIdx.x) >> 6;
    int lane = threadIdx.x & 63;
    if (wave >= N) return;
    int i = wave;
    const float2* base = (const float2*)hs;
    float2 acc = base[(size_t)i * 64 + lane];
    float2 acc2 = make_float2(0.f, 0.f);
    int k0 = rp[i], k1 = rp[i + 1];
    int k = k0;
    for (; k + 1 < k1; k += 2) {
        int j0 = colx[k];
        int j1 = colx[k + 1];
        float2 v0 = base[(size_t)j0 * 64 + lane];
        float2 v1 = base[(size_t)j1 * 64 + lane];
        acc.x += v0.x; acc.y += v0.y;
        acc2.x += v1.x; acc2.y += v1.y;
    }
    if (k < k1) {
        int j0 = colx[k];
        float2 v0 = base[(size_t)j0 * 64 + lane];
        acc.x += v0.x; acc.y += v0.y;
    }
    acc.x += acc2.x; acc.y += acc2.y;
    float d = dinv[i];
    float2 b = ((const float2*)bias)[lane];
    float2 o;
    o.x = fmaf(acc.x, d, b.x);
    o.y = fmaf(acc.y, d, b.y);
    ((float2*)out)[(size_t)i * 64 + lane] = o;
}

// ---------------- BN stats: sums[c] = sum_i x[i][c], sums[128+c] = sum_i x[i][c]^2 ----------------

__global__ __launch_bounds__(256) void k_stats(const float* __restrict__ x, int N,
                                               float* __restrict__ sums) {
    int lane = threadIdx.x & 63;
    int wv = threadIdx.x >> 6;
    int gw = blockIdx.x * 4 + wv;
    int stride = gridDim.x * 4;
    const float2* b = (const float2*)x;
    float2 s = make_float2(0.f, 0.f), q = make_float2(0.f, 0.f);
    for (int i = gw; i < N; i += stride) {
        float2 v = b[(size_t)i * 64 + lane];
        s.x += v.x; s.y += v.y;
        q.x += v.x * v.x; q.y += v.y * v.y;
    }
    __shared__ float ls[4][128];
    __shared__ float lq[4][128];
    ls[wv][2 * lane] = s.x; ls[wv][2 * lane + 1] = s.y;
    lq[wv][2 * lane] = q.x; lq[wv][2 * lane + 1] = q.y;
    __syncthreads();
    int t = threadIdx.x;
    if (t < 128) {
        float ts = ls[0][t] + ls[1][t] + ls[2][t] + ls[3][t];
        float tq = lq[0][t] + lq[1][t] + lq[2][t] + lq[3][t];
        atomicAdd(&sums[t], ts);
        atomicAdd(&sums[128 + t], tq);
    }
}

__global__ void k_bnp(const float* __restrict__ sums, const float* __restrict__ g,
                      const float* __restrict__ be, int N, float* __restrict__ scale,
                      float* __restrict__ shift) {
    int c = threadIdx.x;
    if (c < 128) {
        float invN = 1.0f / (float)N;
        float mu = sums[c] * invN;
        float var = sums[128 + c] * invN - mu * mu;
        var = fmaxf(var, 0.f);
        float s = g[c] * rsqrtf(var + 1e-5f);
        scale[c] = s;
        shift[c] = fmaf(-mu, s, be[c]);
    }
}

// ---------------- Pooling: one block per graph ----------------

__global__ __launch_bounds__(256) void k_pool(const float* __restrict__ x,
                                              const int* __restrict__ gptr,
                                              const float* __restrict__ scale,
                                              const float* __restrict__ shift,
                                              float* __restrict__ pooled) {
    int g = blockIdx.x;
    int t = threadIdx.x;
    int c = t & 127, half = t >> 7;
    int r0 = gptr[g], r1 = gptr[g + 1];
    float s = scale[c], h = shift[c];
    float acc = 0.f;
    for (int r = r0 + half; r < r1; r += 2) {
        float v = x[(size_t)r * 128 + c];
        acc += fmaxf(fmaf(v, s, h), 0.f);
    }
    __shared__ float ls[256];
    ls[t] = acc;
    __syncthreads();
    if (t < 128) {
        float tot = ls[t] + ls[t + 128];
        float cntf = (float)(r1 - r0);
        pooled[g * 128 + t] = tot / fmaxf(cntf, 1.f);
    }
}

// ---------------- Head: out[g][o] = pooled[g] @ Wout[:,o] + bout[o] ----------------

__global__ __launch_bounds__(64) void k_final(const float* __restrict__ pooled,
                                              const float* __restrict__ Wout,
                                              const float* __restrict__ bout,
                                              float* __restrict__ out, int O) {
    int g = blockIdx.x, o = threadIdx.x;
    float acc = bout[o];
    for (int c = 0; c < 128; c++) acc = fmaf(pooled[g * 128 + c], Wout[c * O + o], acc);
    out[g * O + o] = acc;
}

// ---------------- Host launch ----------------

extern "C" void kernel_launch(void* const* d_in, const int* in_sizes, int n_in,
                              void* d_out, int out_size, void* d_ws, size_t ws_size,
                              hipStream_t stream) {
    const float* x    = (const float*)d_in[0];
    const int*   edge = (const int*)d_in[1];
    const int*   batch= (const int*)d_in[2];
    const float* W0   = (const float*)d_in[4];
    const float* b0   = (const float*)d_in[5];
    const float* g0   = (const float*)d_in[6];
    const float* be0  = (const float*)d_in[7];
    const float* W1   = (const float*)d_in[8];
    const float* b1   = (const float*)d_in[9];
    const float* g1   = (const float*)d_in[10];
    const float* be1  = (const float*)d_in[11];
    const float* Wout = (const float*)d_in[12];
    const float* bout = (const float*)d_in[13];
    float* out = (float*)d_out;

    const int Hh  = in_sizes[5];              // 128
    const int Fin = in_sizes[4] / Hh;         // 128
    const int N   = in_sizes[0] / Fin;        // 100000
    const int E   = in_sizes[1] / 2;          // 1600000
    const int O   = in_sizes[13];             // 64
    const int G   = out_size / O;             // 128
    (void)Hh; (void)n_in; (void)ws_size;

    char* p = (char*)d_ws;
    auto alloc = [&](size_t bytes) -> void* {
        void* r = (void*)p;
        p += (bytes + 255) & ~(size_t)255;
        return r;
    };
    float* A      = (float*)alloc((size_t)N * 128 * 4);
    float* B      = (float*)alloc((size_t)N * 128 * 4);
    float* dinv   = (float*)alloc((size_t)N * 4);
    int*   cnt    = (int*)alloc((size_t)N * 4);
    int*   rp     = (int*)alloc((size_t)(N + 1) * 4);
    int*   cursor = (int*)alloc((size_t)N * 4);
    int*   colx   = (int*)alloc((size_t)E * 4);
    int*   bsum   = (int*)alloc(1024 * 4);
    int*   boff   = (int*)alloc(1024 * 4);
    float* sums   = (float*)alloc(512 * 4);   // [sum1|sq1|sum2|sq2]
    float* bn     = (float*)alloc(512 * 4);   // [scale1|shift1|scale2|shift2]
    int*   gptr   = (int*)alloc((size_t)(G + 1) * 4);
    float* pooled = (float*)alloc((size_t)G * 128 * 4);

    hipMemsetAsync(cnt, 0, (size_t)N * 4, stream);
    hipMemsetAsync(sums, 0, 512 * 4, stream);

    const int* src = edge;
    const int* dst = edge + E;

    k_count<<<(E + 255) / 256, 256, 0, stream>>>(dst, E, cnt);
    k_dinv<<<(N + 255) / 256, 256, 0, stream>>>(cnt, dinv, N);
    k_gptr<<<(G + 64) / 64, 64, 0, stream>>>(batch, N, G, gptr);
    int NB = (N + 1023) / 1024;
    k_scan1<<<NB, 1024, 0, stream>>>(cnt, N, rp, bsum);
    k_scan2<<<1, 1024, 0, stream>>>(bsum, NB, boff);
    k_scan3<<<(N + 255) / 256, 256, 0, stream>>>(rp, boff, N, E, cursor);
    k_fill<<<(E + 255) / 256, 256, 0, stream>>>(src, dst, E, cursor, colx);

    // Layer 1
    k_gemm<false><<<(N + 63) / 64, 256, 0, stream>>>(x, W0, nullptr, nullptr, dinv, A, N);
    k_agg<<<(N + 3) / 4, 256, 0, stream>>>(A, rp, colx, dinv, b0, B, N);
    k_stats<<<512, 256, 0, stream>>>(B, N, sums);
    k_bnp<<<1, 128, 0, stream>>>(sums, g0, be0, N, bn, bn + 128);

    // Layer 2 (BN+ReLU fused into GEMM loads)
    k_gemm<true><<<(N + 63) / 64, 256, 0, stream>>>(B, W1, bn, bn + 128, dinv, A, N);
    k_agg<<<(N + 3) / 4, 256, 0, stream>>>(A, rp, colx, dinv, b1, B, N);
    k_stats<<<512, 256, 0, stream>>>(B, N, sums + 256);
    k_bnp<<<1, 128, 0, stream>>>(sums + 256, g1, be1, N, bn + 256, bn + 384);

    // Pool + head (BN+ReLU fused into pooling loads)
    k_pool<<<G, 256, 0, stream>>>(B, gptr, bn + 256, bn + 384, pooled);
    k_final<<<G, 64, 0, stream>>>(pooled, Wout, bout, out, O);
}

// Round 3
// 801.970 us; speedup vs baseline: 1.4698x; 1.1084x over previous
//
#include <hip/hip_runtime.h>
#include <hip/hip_bf16.h>

typedef _Float16 half4_t __attribute__((ext_vector_type(4)));
typedef _Float16 half2_t __attribute__((ext_vector_type(2)));

// ---------------- CSR build ----------------

__global__ void k_count(const int* __restrict__ dst, int E, int* __restrict__ cnt) {
    int e = blockIdx.x * blockDim.x + threadIdx.x;
    if (e < E) atomicAdd(&cnt[dst[e]], 1);
}

__global__ void k_dinv(const int* __restrict__ cnt, float* __restrict__ dinv, int N) {
    int i = blockIdx.x * blockDim.x + threadIdx.x;
    if (i < N) dinv[i] = rsqrtf((float)(cnt[i] + 1));  // +1 self-loop
}

// gptr[g] = first index i where batch[i] >= g (batch is sorted); gptr[G] = N.
__global__ void k_gptr(const int* __restrict__ batch, int N, int G, int* __restrict__ gptr) {
    int g = blockIdx.x * blockDim.x + threadIdx.x;
    if (g > G) return;
    int lo = 0, hi = N;
    while (lo < hi) {
        int mid = (lo + hi) >> 1;
        if (batch[mid] < g) lo = mid + 1; else hi = mid;
    }
    gptr[g] = lo;
}

__global__ __launch_bounds__(1024) void k_scan1(const int* __restrict__ cnt, int N,
                                                int* __restrict__ rp, int* __restrict__ bsum) {
    __shared__ int s[1024];
    int t = threadIdx.x;
    int i = blockIdx.x * 1024 + t;
    int v = (i < N) ? cnt[i] : 0;
    s[t] = v;
    __syncthreads();
    for (int off = 1; off < 1024; off <<= 1) {
        int u = (t >= off) ? s[t - off] : 0;
        __syncthreads();
        s[t] += u;
        __syncthreads();
    }
    if (i < N) rp[i] = s[t] - v;  // exclusive within block
    if (t == 1023) bsum[blockIdx.x] = s[1023];
}

__global__ __launch_bounds__(1024) void k_scan2(const int* __restrict__ bsum, int NB,
                                                int* __restrict__ boff) {
    __shared__ int s[1024];
    int t = threadIdx.x;
    int v = (t < NB) ? bsum[t] : 0;
    s[t] = v;
    __syncthreads();
    for (int off = 1; off < 1024; off <<= 1) {
        int u = (t >= off) ? s[t - off] : 0;
        __syncthreads();
        s[t] += u;
        __syncthreads();
    }
    if (t < NB) boff[t] = s[t] - v;
}

__global__ void k_scan3(int* __restrict__ rp, const int* __restrict__ boff, int N, int E,
                        int* __restrict__ cursor) {
    int i = blockIdx.x * blockDim.x + threadIdx.x;
    if (i < N) {
        int v = rp[i] + boff[i >> 10];
        rp[i] = v;
        cursor[i] = v;
    }
    if (blockIdx.x == 0 && threadIdx.x == 0) rp[N] = E;
}

__global__ void k_fill(const int* __restrict__ src, const int* __restrict__ dst, int E,
                       int* __restrict__ cursor, int* __restrict__ colx) {
    int e = blockIdx.x * blockDim.x + threadIdx.x;
    if (e < E) {
        int d = dst[e];
        int pos = atomicAdd(&cursor[d], 1);
        colx[pos] = src[e];
    }
}

// ---------------- GEMM: out[row] = (act(X[row]) @ W) * dinv[row]  (fp16 output) ----------------
// act = identity (layer 1) or BN+ReLU (layer 2). K = 128, Cout = 128.

template <bool BN>
__global__ __launch_bounds__(256) void k_gemm(const float* __restrict__ X,
                                              const float* __restrict__ W,
                                              const float* __restrict__ scale,
                                              const float* __restrict__ shift,
                                              const float* __restrict__ dinv,
                                              _Float16* __restrict__ out, int N) {
    __shared__ float Ws[128 * 128];
    __shared__ float sc[128], sh[128];
    int t = threadIdx.x;
    {
        const float4* W4 = (const float4*)W;
        float4* Ws4 = (float4*)Ws;
        #pragma unroll
        for (int i = 0; i < 16; i++) Ws4[t + i * 256] = W4[t + i * 256];
        if (BN && t < 128) { sc[t] = scale[t]; sh[t] = shift[t]; }
    }
    __syncthreads();

    int r0 = blockIdx.x * 64 + (t >> 3) * 2;
    int r1 = r0 + 1;
    bool v0 = r0 < N, v1 = r1 < N;
    const float* x0 = X + (size_t)(v0 ? r0 : N - 1) * 128;
    const float* x1 = X + (size_t)(v1 ? r1 : N - 1) * 128;
    int cbase = (t & 7) * 4;

    float acc0[16], acc1[16];
    #pragma unroll
    for (int j = 0; j < 16; j++) { acc0[j] = 0.f; acc1[j] = 0.f; }

    for (int kk = 0; kk < 128; kk += 4) {
        float4 a4 = *(const float4*)(x0 + kk);
        float4 b4 = *(const float4*)(x1 + kk);
        float av[4] = {a4.x, a4.y, a4.z, a4.w};
        float bv[4] = {b4.x, b4.y, b4.z, b4.w};
        #pragma unroll
        for (int j = 0; j < 4; j++) {
            float a = av[j], b = bv[j];
            if (BN) {
                float s = sc[kk + j], h = sh[kk + j];
                a = fmaxf(fmaf(a, s, h), 0.f);
                b = fmaxf(fmaf(b, s, h), 0.f);
            }
            const float* wrow = Ws + (kk + j) * 128 + cbase;
            #pragma unroll
            for (int q = 0; q < 4; q++) {
                float4 w = *(const float4*)(wrow + q * 32);
                acc0[q * 4 + 0] = fmaf(a, w.x, acc0[q * 4 + 0]);
                acc0[q * 4 + 1] = fmaf(a, w.y, acc0[q * 4 + 1]);
                acc0[q * 4 + 2] = fmaf(a, w.z, acc0[q * 4 + 2]);
                acc0[q * 4 + 3] = fmaf(a, w.w, acc0[q * 4 + 3]);
                acc1[q * 4 + 0] = fmaf(b, w.x, acc1[q * 4 + 0]);
                acc1[q * 4 + 1] = fmaf(b, w.y, acc1[q * 4 + 1]);
                acc1[q * 4 + 2] = fmaf(b, w.z, acc1[q * 4 + 2]);
                acc1[q * 4 + 3] = fmaf(b, w.w, acc1[q * 4 + 3]);
            }
        }
    }

    if (v0) {
        float d = dinv[r0];
        _Float16* o = out + (size_t)r0 * 128 + cbase;
        #pragma unroll
        for (int q = 0; q < 4; q++) {
            half4_t h;
            h.x = (_Float16)(acc0[q * 4 + 0] * d);
            h.y = (_Float16)(acc0[q * 4 + 1] * d);
            h.z = (_Float16)(acc0[q * 4 + 2] * d);
            h.w = (_Float16)(acc0[q * 4 + 3] * d);
            *(half4_t*)(o + q * 32) = h;
        }
    }
    if (v1) {
        float d = dinv[r1];
        _Float16* o = out + (size_t)r1 * 128 + cbase;
        #pragma unroll
        for (int q = 0; q < 4; q++) {
            half4_t h;
            h.x = (_Float16)(acc1[q * 4 + 0] * d);
            h.y = (_Float16)(acc1[q * 4 + 1] * d);
            h.z = (_Float16)(acc1[q * 4 + 2] * d);
            h.w = (_Float16)(acc1[q * 4 + 3] * d);
            *(half4_t*)(o + q * 32) = h;
        }
    }
}

// ---------------- Aggregation: out[i] = dinv[i]*(hs[i] + sum_{j in in(i)} hs[j]) + b ----------------
// One wave per node; lane L holds cols {2L, 2L+1} (half2 gather, fp32 accumulate).

__global__ __launch_bounds__(256) void k_agg(const _Float16* __restrict__ hs,
                                             const int* __restrict__ rp,
                                             const int* __restrict__ colx,
                                             const float* __restrict__ dinv,
                                             const float* __restrict__ bias,
                                             float* __restrict__ out, int N) {
    int wave = (blockIdx.x * 256 + threadIdx.x) >> 6;
    int lane = threadIdx.x & 63;
    if (wave >= N) return;
    int i = wave;
    const half2_t* base = (const half2_t*)hs;
    half2_t h0 = base[(size_t)i * 64 + lane];
    float2 acc = make_float2((float)h0.x, (float)h0.y);
    float2 acc2 = make_float2(0.f, 0.f);
    int k0 = rp[i], k1 = rp[i + 1];
    int k = k0;
    for (; k + 1 < k1; k += 2) {
        int j0 = colx[k];
        int j1 = colx[k + 1];
        half2_t v0 = base[(size_t)j0 * 64 + lane];
        half2_t v1 = base[(size_t)j1 * 64 + lane];
        acc.x += (float)v0.x; acc.y += (float)v0.y;
        acc2.x += (float)v1.x; acc2.y += (float)v1.y;
    }
    if (k < k1) {
        int j0 = colx[k];
        half2_t v0 = base[(size_t)j0 * 64 + lane];
        acc.x += (float)v0.x; acc.y += (float)v0.y;
    }
    acc.x += acc2.x; acc.y += acc2.y;
    float d = dinv[i];
    float2 b = ((const float2*)bias)[lane];
    float2 o;
    o.x = fmaf(acc.x, d, b.x);
    o.y = fmaf(acc.y, d, b.y);
    ((float2*)out)[(size_t)i * 64 + lane] = o;
}

// ---------------- BN stats: sums[c] = sum_i x[i][c], sums[128+c] = sum_i x[i][c]^2 ----------------

__global__ __launch_bounds__(256) void k_stats(const float* __restrict__ x, int N,
                                               float* __restrict__ sums) {
    int lane = threadIdx.x & 63;
    int wv = threadIdx.x >> 6;
    int gw = blockIdx.x * 4 + wv;
    int stride = gridDim.x * 4;
    const float2* b = (const float2*)x;
    float2 s = make_float2(0.f, 0.f), q = make_float2(0.f, 0.f);
    for (int i = gw; i < N; i += stride) {
        float2 v = b[(size_t)i * 64 + lane];
        s.x += v.x; s.y += v.y;
        q.x += v.x * v.x; q.y += v.y * v.y;
    }
    __shared__ float ls[4][128];
    __shared__ float lq[4][128];
    ls[wv][2 * lane] = s.x; ls[wv][2 * lane + 1] = s.y;
    lq[wv][2 * lane] = q.x; lq[wv][2 * lane + 1] = q.y;
    __syncthreads();
    int t = threadIdx.x;
    if (t < 128) {
        float ts = ls[0][t] + ls[1][t] + ls[2][t] + ls[3][t];
        float tq = lq[0][t] + lq[1][t] + lq[2][t] + lq[3][t];
        atomicAdd(&sums[t], ts);
        atomicAdd(&sums[128 + t], tq);
    }
}

__global__ void k_bnp(const float* __restrict__ sums, const float* __restrict__ g,
                      const float* __restrict__ be, int N, float* __restrict__ scale,
                      float* __restrict__ shift) {
    int c = threadIdx.x;
    if (c < 128) {
        float invN = 1.0f / (float)N;
        float mu = sums[c] * invN;
        float var = sums[128 + c] * invN - mu * mu;
        var = fmaxf(var, 0.f);
        float s = g[c] * rsqrtf(var + 1e-5f);
        scale[c] = s;
        shift[c] = fmaf(-mu, s, be[c]);
    }
}

// ---------------- Pooling: one block per graph ----------------

__global__ __launch_bounds__(256) void k_pool(const float* __restrict__ x,
                                              const int* __restrict__ gptr,
                                              const float* __restrict__ scale,
                                              const float* __restrict__ shift,
                                              float* __restrict__ pooled) {
    int g = blockIdx.x;
    int t = threadIdx.x;
    int c = t & 127, half = t >> 7;
    int r0 = gptr[g], r1 = gptr[g + 1];
    float s = scale[c], h = shift[c];
    float acc = 0.f;
    for (int r = r0 + half; r < r1; r += 2) {
        float v = x[(size_t)r * 128 + c];
        acc += fmaxf(fmaf(v, s, h), 0.f);
    }
    __shared__ float ls[256];
    ls[t] = acc;
    __syncthreads();
    if (t < 128) {
        float tot = ls[t] + ls[t + 128];
        float cntf = (float)(r1 - r0);
        pooled[g * 128 + t] = tot / fmaxf(cntf, 1.f);
    }
}

// ---------------- Head: out[g][o] = pooled[g] @ Wout[:,o] + bout[o] ----------------

__global__ __launch_bounds__(64) void k_final(const float* __restrict__ pooled,
                                              const float* __restrict__ Wout,
                                              const float* __restrict__ bout,
                                              float* __restrict__ out, int O) {
    int g = blockIdx.x, o = threadIdx.x;
    float acc = bout[o];
    for (int c = 0; c < 128; c++) acc = fmaf(pooled[g * 128 + c], Wout[c * O + o], acc);
    out[g * O + o] = acc;
}

// ---------------- Host launch ----------------

extern "C" void kernel_launch(void* const* d_in, const int* in_sizes, int n_in,
                              void* d_out, int out_size, void* d_ws, size_t ws_size,
                              hipStream_t stream) {
    const float* x    = (const float*)d_in[0];
    const int*   edge = (const int*)d_in[1];
    const int*   batch= (const int*)d_in[2];
    const float* W0   = (const float*)d_in[4];
    const float* b0   = (const float*)d_in[5];
    const float* g0   = (const float*)d_in[6];
    const float* be0  = (const float*)d_in[7];
    const float* W1   = (const float*)d_in[8];
    const float* b1   = (const float*)d_in[9];
    const float* g1   = (const float*)d_in[10];
    const float* be1  = (const float*)d_in[11];
    const float* Wout = (const float*)d_in[12];
    const float* bout = (const float*)d_in[13];
    float* out = (float*)d_out;

    const int Hh  = in_sizes[5];              // 128
    const int Fin = in_sizes[4] / Hh;         // 128
    const int N   = in_sizes[0] / Fin;        // 100000
    const int E   = in_sizes[1] / 2;          // 1600000
    const int O   = in_sizes[13];             // 64
    const int G   = out_size / O;             // 128
    (void)Hh; (void)n_in; (void)ws_size;

    char* p = (char*)d_ws;
    auto alloc = [&](size_t bytes) -> void* {
        void* r = (void*)p;
        p += (bytes + 255) & ~(size_t)255;
        return r;
    };
    _Float16* A   = (_Float16*)alloc((size_t)N * 128 * 2);   // fp16 gather table
    float* B      = (float*)alloc((size_t)N * 128 * 4);
    float* dinv   = (float*)alloc((size_t)N * 4);
    int*   cnt    = (int*)alloc((size_t)N * 4);
    int*   rp     = (int*)alloc((size_t)(N + 1) * 4);
    int*   cursor = (int*)alloc((size_t)N * 4);
    int*   colx   = (int*)alloc((size_t)E * 4);
    int*   bsum   = (int*)alloc(1024 * 4);
    int*   boff   = (int*)alloc(1024 * 4);
    float* sums   = (float*)alloc(512 * 4);   // [sum1|sq1|sum2|sq2]
    float* bn     = (float*)alloc(512 * 4);   // [scale1|shift1|scale2|shift2]
    int*   gptr   = (int*)alloc((size_t)(G + 1) * 4);
    float* pooled = (float*)alloc((size_t)G * 128 * 4);

    hipMemsetAsync(cnt, 0, (size_t)N * 4, stream);
    hipMemsetAsync(sums, 0, 512 * 4, stream);

    const int* src = edge;
    const int* dst = edge + E;

    k_count<<<(E + 255) / 256, 256, 0, stream>>>(dst, E, cnt);
    k_dinv<<<(N + 255) / 256, 256, 0, stream>>>(cnt, dinv, N);
    k_gptr<<<(G + 64) / 64, 64, 0, stream>>>(batch, N, G, gptr);
    int NB = (N + 1023) / 1024;
    k_scan1<<<NB, 1024, 0, stream>>>(cnt, N, rp, bsum);
    k_scan2<<<1, 1024, 0, stream>>>(bsum, NB, boff);
    k_scan3<<<(N + 255) / 256, 256, 0, stream>>>(rp, boff, N, E, cursor);
    k_fill<<<(E + 255) / 256, 256, 0, stream>>>(src, dst, E, cursor, colx);

    // Layer 1
    k_gemm<false><<<(N + 63) / 64, 256, 0, stream>>>(x, W0, nullptr, nullptr, dinv, A, N);
    k_agg<<<(N + 3) / 4, 256, 0, stream>>>(A, rp, colx, dinv, b0, B, N);
    k_stats<<<512, 256, 0, stream>>>(B, N, sums);
    k_bnp<<<1, 128, 0, stream>>>(sums, g0, be0, N, bn, bn + 128);

    // Layer 2 (BN+ReLU fused into GEMM loads)
    k_gemm<true><<<(N + 63) / 64, 256, 0, stream>>>(B, W1, bn, bn + 128, dinv, A, N);
    k_agg<<<(N + 3) / 4, 256, 0, stream>>>(A, rp, colx, dinv, b1, B, N);
    k_stats<<<512, 256, 0, stream>>>(B, N, sums + 256);
    k_bnp<<<1, 128, 0, stream>>>(sums + 256, g1, be1, N, bn + 256, bn + 384);

    // Pool + head (BN+ReLU fused into pooling loads)
    k_pool<<<G, 256, 0, stream>>>(B, gptr, bn + 256, bn + 384, pooled);
    k_final<<<G, 64, 0, stream>>>(pooled, Wout, bout, out, O);
}